// Round 5
// baseline (661.383 us; speedup 1.0000x reference)
//
#include <hip/hip_runtime.h>
#include <math.h>

#define B_   16
#define CIN  64
#define COUT 64
#define H_   256
#define W_   256

typedef short s16x8  __attribute__((ext_vector_type(8)));
typedef float f32x16 __attribute__((ext_vector_type(16)));

// Split fp32 into two bf16 (truncation): v = hi + lo + O(2^-16 * v)
__device__ __forceinline__ void split_bf16(float v, unsigned short& hi, unsigned short& lo) {
    unsigned u = __float_as_uint(v);
    hi = (unsigned short)(u >> 16);
    float hif = __uint_as_float(u & 0xffff0000u);
    lo = (unsigned short)(__float_as_uint(v - hif) >> 16);
}

// ---------------------------------------------------------------------------
// 1) pooled[b*64+c] = mean over H*W of inputs[b][c][:][:]
__global__ __launch_bounds__(256) void pool_kernel(const float* __restrict__ x,
                                                   float* __restrict__ pooled) {
    const int plane = blockIdx.x;  // 0..1023 = b*64+c
    const float4* p = (const float4*)(x + (size_t)plane * (H_ * W_));
    float s = 0.f;
    for (int i = threadIdx.x; i < (H_ * W_) / 4; i += 256) {
        float4 v = p[i];
        s += (v.x + v.y) + (v.z + v.w);
    }
    #pragma unroll
    for (int off = 32; off > 0; off >>= 1) s += __shfl_down(s, off);
    __shared__ float red[4];
    if ((threadIdx.x & 63) == 0) red[threadIdx.x >> 6] = s;
    __syncthreads();
    if (threadIdx.x == 0)
        pooled[plane] = (red[0] + red[1] + red[2] + red[3]) * (1.f / (H_ * W_));
}

// ---------------------------------------------------------------------------
// 2) routing[b*4+e] = sigmoid(dot(pooled[b], fc_w[e]) + fc_b[e])
__global__ void routing_kernel(const float* __restrict__ pooled,
                               const float* __restrict__ fc_w,
                               const float* __restrict__ fc_b,
                               float* __restrict__ routing) {
    const int tid = threadIdx.x;          // 64 threads
    const int b = tid >> 2, e = tid & 3;
    float s = fc_b[e];
    for (int c = 0; c < CIN; ++c) s += pooled[b * CIN + c] * fc_w[e * CIN + c];
    routing[b * 4 + e] = 1.f / (1.f + expf(-s));
}

// ---------------------------------------------------------------------------
// 3) mixed weights in exact MFMA A-fragment order, bf16 hi/lo.
// Per (b, q-chunk): 36 fragments of 512 shorts:
//   frag f = tap*4 + half*2 + mb  (tap 0..8, half 0=hi 1=lo, mb 0..1)
//   frag layout: [lane(64)][8]: lane l -> oc = mb*32 + (l&31),
//                               ic = q*16 + (l>>5)*8 + j
__global__ __launch_bounds__(256) void mix_kernel(const float* __restrict__ routing,
                                                  const float* __restrict__ weight,
                                                  unsigned short* __restrict__ mixed) {
    const int gid = blockIdx.x * 256 + threadIdx.x;   // 0..65535
    const int icL = gid & 15;
    const int oc  = (gid >> 4) & 63;
    const int q   = (gid >> 10) & 3;
    const int b   = gid >> 12;
    const int ic  = q * 16 + icL;

    float r[4];
    #pragma unroll
    for (int e = 0; e < 4; ++e) r[e] = routing[b * 4 + e];

    float s[9];
    #pragma unroll
    for (int t = 0; t < 9; ++t) s[t] = 0.f;
    #pragma unroll
    for (int e = 0; e < 4; ++e) {
        const float* wp = weight + (((size_t)e * COUT + oc) * CIN + ic) * 9;
        #pragma unroll
        for (int t = 0; t < 9; ++t) s[t] = fmaf(r[e], wp[t], s[t]);
    }
    unsigned short* base = mixed + (size_t)(b * 4 + q) * 18432;
    const int mb = oc >> 5;
    const int l  = (oc & 31) + ((icL >> 3) << 5);
    const int j  = icL & 7;
    #pragma unroll
    for (int t = 0; t < 9; ++t) {
        unsigned short hi, lo;
        split_bf16(s[t], hi, lo);
        base[(t * 4 + 0 + mb) * 512 + l * 8 + j] = hi;   // half 0
        base[(t * 4 + 2 + mb) * 512 + l * 8 + j] = lo;   // half 1
    }
}

// ---------------------------------------------------------------------------
// 4) conv: tap-decomposed implicit GEMM, split-bf16 3-pass.
// B (input) in DOUBLE-BUFFERED LDS, plane-major conflict-free layout:
//   chunk(buf, plane, pos) = buf*1360 + plane*340 + pos, plane = hl*2 + ks.
//   A B-read's 32 lanes hit 32 consecutive 16B chunks -> zero bank conflicts
//   (verified R4: SQ_LDS_BANK_CONFLICT = 0).
// Pipeline (one barrier per q):
//   issue q+1 global loads -> MFMA phase on buf[cur] (~4.7K cyc hides HBM
//   latency) -> convert+write buf[cur^1] -> barrier.
//   Safety: writes target the buffer no wave reads this iteration; each wave
//   writes only after finishing its own reads of buf[cur], and the barrier
//   orders all writes before q+1's reads.
// kw-outer MFMA loop: cache 4 B rows x {hi,lo} in regs, batch 12 A global
// loads (L2-resident fragment order) per kw ahead of a 36-MFMA burst.
// Grid: 4096 1D with bijective XCD-chunked swizzle (4096%8==0).
__global__ __launch_bounds__(256, 2) void conv_kernel(const float* __restrict__ x,
                                                      const unsigned short* __restrict__ wmix,
                                                      float* __restrict__ y) {
    __shared__ __align__(16) unsigned short in_s[2 * 4 * 340 * 8];   // 43520 B

    const int tid  = threadIdx.x;
    const int lane = tid & 63;
    const int wv   = tid >> 6;
    const int n    = lane & 31;       // MFMA col / output w-in-tile
    const int kseg = lane >> 5;       // k-half select

    // XCD-chunked bijective swizzle: consecutive logical tiles on one XCD
    const int bid = blockIdx.x;                 // 0..4095
    const int wg  = (bid & 7) * 512 + (bid >> 3);
    const int w0 = (wg & 7) * 32;
    const int h0 = ((wg >> 3) & 31) * 8;
    const int b  = wg >> 8;

    // staging: 340 halo positions; thread covers p0 (+p1 if tid<84)
    const int p0 = tid;
    const int r0 = p0 / 34, c0 = p0 - r0 * 34;
    const int p1 = tid + 256;
    const int r1 = p1 / 34, c1 = p1 - r1 * 34;
    const bool has1 = (p1 < 340);

    const int gh0 = h0 - 1 + r0, gw0 = w0 - 1 + c0;
    const int gh1 = h0 - 1 + r1, gw1 = w0 - 1 + c1;
    const bool ok0 = ((unsigned)gh0 < H_) && ((unsigned)gw0 < W_);
    const bool ok1 = has1 && ((unsigned)gh1 < H_) && ((unsigned)gw1 < W_);

    const float* xb = x + (size_t)b * CIN * H_ * W_;
    const float* g0 = xb + (ok0 ? (gh0 * W_ + gw0) : 0);
    const float* g1 = xb + (ok1 ? (gh1 * W_ + gw1) : 0);

    #define LOAD16(dst, gp, okf, qq) do {                                   \
        const float* _p = (gp) + (size_t)(qq) * 16 * (H_ * W_);             \
        _Pragma("unroll")                                                   \
        for (int _i = 0; _i < 16; ++_i)                                     \
            dst[_i] = (okf) ? _p[(size_t)_i * (H_ * W_)] : 0.f;             \
    } while (0)

    // pack 16 floats -> 4 plane-major chunk writes into buffer bb
    #define STAGE(bb, pp, regs) do {                                        \
        s16x8 _h0, _h1, _l0, _l1;                                           \
        _Pragma("unroll")                                                   \
        for (int _i = 0; _i < 8; ++_i) {                                    \
            unsigned short _h, _l;                                          \
            split_bf16(regs[_i], _h, _l);                                   \
            _h0[_i] = (short)_h; _l0[_i] = (short)_l;                       \
            split_bf16(regs[8 + _i], _h, _l);                               \
            _h1[_i] = (short)_h; _l1[_i] = (short)_l;                       \
        }                                                                   \
        ((s16x8*)in_s)[(bb) * 1360 + 0 * 340 + (pp)] = _h0;                 \
        ((s16x8*)in_s)[(bb) * 1360 + 1 * 340 + (pp)] = _h1;                 \
        ((s16x8*)in_s)[(bb) * 1360 + 2 * 340 + (pp)] = _l0;                 \
        ((s16x8*)in_s)[(bb) * 1360 + 3 * 340 + (pp)] = _l1;                 \
    } while (0)

    f32x16 acc[2][2];
    #pragma unroll
    for (int mb = 0; mb < 2; ++mb)
        #pragma unroll
        for (int nb = 0; nb < 2; ++nb)
            #pragma unroll
            for (int j = 0; j < 16; ++j) acc[mb][nb][j] = 0.f;

    const unsigned short* wb = wmix + (size_t)b * 4 * 18432 + lane * 8;

    float xr0[16], xr1[16];

    // prologue: load + stage q=0 into buf 0
    LOAD16(xr0, g0, ok0, 0);
    if (has1) LOAD16(xr1, g1, ok1, 0);
    STAGE(0, p0, xr0);
    if (has1) STAGE(0, p1, xr1);
    __syncthreads();

    #pragma unroll 1
    for (int q = 0; q < 4; ++q) {
        const int cur = q & 1;
        // T14: issue next chunk's global loads before the MFMA phase
        if (q < 3) {
            LOAD16(xr0, g0, ok0, q + 1);
            if (has1) LOAD16(xr1, g1, ok1, q + 1);
        }
        const unsigned short* wq = wb + q * 18432;
        const s16x8* bs = (const s16x8*)in_s + cur * 1360;

        #pragma unroll
        for (int kw = 0; kw < 3; ++kw) {
            // A fragments for the 3 taps of this kw (global, L2-hit, coalesced)
            s16x8 aH[3][2], aL[3][2];
            #pragma unroll
            for (int kh = 0; kh < 3; ++kh) {
                const int tap = kh * 3 + kw;
                #pragma unroll
                for (int mb = 0; mb < 2; ++mb) {
                    aH[kh][mb] = *(const s16x8*)(wq + (tap * 4 + 0 + mb) * 512);
                    aL[kh][mb] = *(const s16x8*)(wq + (tap * 4 + 2 + mb) * 512);
                }
            }
            // B row-cache: 4 rows x {hi,lo}, conflict-free consecutive-chunk reads
            s16x8 bh[4], bl[4];
            #pragma unroll
            for (int r = 0; r < 4; ++r) {
                const int pos = (wv * 2 + r) * 34 + n + kw;
                bh[r] = bs[(0 + kseg) * 340 + pos];
                bl[r] = bs[(2 + kseg) * 340 + pos];
            }
            // 36 MFMAs for this kw
            #pragma unroll
            for (int kh = 0; kh < 3; ++kh) {
                #pragma unroll
                for (int nb = 0; nb < 2; ++nb) {
                    const int r = nb + kh;
                    #pragma unroll
                    for (int mb = 0; mb < 2; ++mb) {
                        acc[mb][nb] = __builtin_amdgcn_mfma_f32_32x32x16_bf16(aH[kh][mb], bh[r], acc[mb][nb], 0, 0, 0);
                        acc[mb][nb] = __builtin_amdgcn_mfma_f32_32x32x16_bf16(aL[kh][mb], bh[r], acc[mb][nb], 0, 0, 0);
                        acc[mb][nb] = __builtin_amdgcn_mfma_f32_32x32x16_bf16(aH[kh][mb], bl[r], acc[mb][nb], 0, 0, 0);
                    }
                }
            }
        }

        // stage q+1 into the other buffer; single barrier orders it for q+1
        if (q < 3) {
            STAGE(cur ^ 1, p0, xr0);
            if (has1) STAGE(cur ^ 1, p1, xr1);
            __syncthreads();
        }
    }

    // epilogue: C/D layout: col = lane&31, row = (r&3)+8*(r>>2)+4*kseg
    #pragma unroll
    for (int mb = 0; mb < 2; ++mb) {
        #pragma unroll
        for (int nb = 0; nb < 2; ++nb) {
            const int hrow = h0 + wv * 2 + nb;
            #pragma unroll
            for (int r = 0; r < 16; ++r) {
                const int oc = mb * 32 + (r & 3) + 8 * (r >> 2) + 4 * kseg;
                y[(((size_t)b * COUT + oc) * H_ + hrow) * W_ + w0 + n] = acc[mb][nb][r];
            }
        }
    }
}

// ---------------------------------------------------------------------------
extern "C" void kernel_launch(void* const* d_in, const int* in_sizes, int n_in,
                              void* d_out, int out_size, void* d_ws, size_t ws_size,
                              hipStream_t stream) {
    const float* x      = (const float*)d_in[0];  // [16,64,256,256]
    const float* weight = (const float*)d_in[1];  // [4,64,64,3,3]
    const float* fc_w   = (const float*)d_in[2];  // [4,64]
    const float* fc_b   = (const float*)d_in[3];  // [4]
    float* out = (float*)d_out;

    float* ws      = (float*)d_ws;
    float* pooled  = ws;                                   // 1024 floats
    float* routing = ws + 1024;                            // 64 floats
    unsigned short* mixed = (unsigned short*)(ws + 1088);  // 1179648 shorts (~2.36 MB)

    pool_kernel<<<B_ * CIN, 256, 0, stream>>>(x, pooled);
    routing_kernel<<<1, 64, 0, stream>>>(pooled, fc_w, fc_b, routing);
    mix_kernel<<<(B_ * 4 * COUT * 16) / 256, 256, 0, stream>>>(routing, weight, mixed);

    conv_kernel<<<4096, 256, 0, stream>>>(x, mixed, out);
}